// Round 1
// baseline (276.389 us; speedup 1.0000x reference)
//
#include <hip/hip_runtime.h>

// ---------------------------------------------------------------------------
// KeypointWeighting: fused MLP-score + projection + compaction on MI355X
//
// dims: B=8 N=16384 C=640 H=256 O=128, M = B*N = 131072
// ref:  h = relu(pf@w1+b1); logit = h@w2+b2; s = sigmoid(logit)
//       feats = (pf*s)@wo + bo = s*(pf@wo) + bo
//       compact rows with s>0.4 per batch; pad zeros; mask=1 on padding
// ---------------------------------------------------------------------------

typedef __attribute__((ext_vector_type(8))) short short8v;
typedef __attribute__((ext_vector_type(4))) float f32x4;

#define M_TOTAL 131072
#define C_DIM 640
#define H_DIM 256
#define O_DIM 128
#define NCOMB 384      // combined cols: 256 (w1) + 128 (wo)
#define TM 64
#define KSTEPS 20      // 640 / 32
#define N_PTS 16384

// ws layout (bytes)
#define WT_OFF     0u          // bf16 [384][640]  = 491520 B
#define SCORES_OFF 491520u     // f32  [131072]    = 524288 B
#define POS_OFF    1015808u    // i32  [131072]    = 524288 B
#define COUNTS_OFF 1540096u    // i32  [8]
#define BCNT_OFF   1540352u    // i32  [1]
#define BLIST_OFF  1540608u    // i32  [4096]
#define G_OFF      1572864u    // f32  [131072][128] = 67108864 B
// total ~68.7 MB

#define OUT_COORD_OFF 16777216  // B*N*O
#define OUT_MASK_OFF  17170432  // + B*N*3

__device__ __forceinline__ unsigned short f2bf_bits(float f) {
  unsigned int u = __builtin_bit_cast(unsigned int, f);
  unsigned int r = (u + 0x7fffu + ((u >> 16) & 1u)) >> 16;  // RNE
  return (unsigned short)r;
}

// K0: pack [w1 | wo] transposed to bf16: Wt[n][k], n<256 -> w1[k][n], else wo[k][n-256]
__global__ __launch_bounds__(256) void convert_w(const float* __restrict__ w1,
                                                 const float* __restrict__ wo,
                                                 unsigned short* __restrict__ Wt,
                                                 int* __restrict__ bcount) {
  int idx = blockIdx.x * 256 + threadIdx.x;  // 384*640 = 245760 = 960*256
  if (idx == 0) *bcount = 0;
  if (idx < NCOMB * C_DIM) {
    int n = idx / C_DIM, k = idx - n * C_DIM;
    float v = (n < H_DIM) ? w1[k * H_DIM + n] : wo[k * O_DIM + (n - H_DIM)];
    Wt[idx] = f2bf_bits(v);
  }
}

// K1: fused GEMM: per 64-row tile, acc[384 cols] = A(64x640,bf16) @ [w1|wo]
// epilogue: logit/score from w1-part (f32 h), raw G from wo-part, borderline list.
__global__ __launch_bounds__(256) void gemm_fused(
    const float* __restrict__ pf, const unsigned short* __restrict__ Wt,
    const float* __restrict__ b1, const float* __restrict__ w2,
    const float* __restrict__ b2, float* __restrict__ scores,
    float* __restrict__ G, int* __restrict__ blist, int* __restrict__ bcount) {
  // LDS layouts are [kgroup][row/col][8 k] so each lane's ds_read_b128 is the
  // exact MFMA fragment (k = 8*(lane>>4) + j).
  __shared__ __align__(16) unsigned short As[4 * 64 * 8];    // 4 KB
  __shared__ __align__(16) unsigned short Bs[4 * NCOMB * 8]; // 24 KB
  __shared__ float lpart[4][64];

  const int tid = threadIdx.x;
  const int lane = tid & 63;
  const int wv = tid >> 6;
  const int m0 = blockIdx.x * TM;
  const int q = lane & 15;   // col within 16x16 tile
  const int p = lane >> 4;   // k-group / row-group selector

  f32x4 acc[6][4];
#pragma unroll
  for (int i = 0; i < 6; ++i)
#pragma unroll
    for (int rt = 0; rt < 4; ++rt) acc[i][rt] = (f32x4){0.f, 0.f, 0.f, 0.f};

  const int ar = tid >> 2;   // A staging: row
  const int akg = tid & 3;   // A staging: k-group

  for (int ks = 0; ks < KSTEPS; ++ks) {
    const int k0 = ks * 32;
    {  // stage A: 64 rows x 32 k, f32 -> bf16
      const float* src = pf + (size_t)(m0 + ar) * C_DIM + k0 + akg * 8;
      float4 f0 = *(const float4*)(src);
      float4 f1 = *(const float4*)(src + 4);
      short8v v;
      v[0] = f2bf_bits(f0.x); v[1] = f2bf_bits(f0.y);
      v[2] = f2bf_bits(f0.z); v[3] = f2bf_bits(f0.w);
      v[4] = f2bf_bits(f1.x); v[5] = f2bf_bits(f1.y);
      v[6] = f2bf_bits(f1.z); v[7] = f2bf_bits(f1.w);
      *(short8v*)&As[(akg * 64 + ar) * 8] = v;
    }
    // stage B: 32 k x 384 cols bf16 (Wt is col-major so 8 k's are contiguous)
#pragma unroll
    for (int u = 0; u < 6; ++u) {
      int idx = tid + u * 256;           // 1536 units
      int n = idx >> 2, kg = idx & 3;
      short8v v = *(const short8v*)(Wt + n * C_DIM + k0 + kg * 8);
      *(short8v*)&Bs[(kg * NCOMB + n) * 8] = v;
    }
    __syncthreads();
    short8v af[4];
#pragma unroll
    for (int rt = 0; rt < 4; ++rt)
      af[rt] = *(const short8v*)&As[(p * 64 + rt * 16 + q) * 8];
    short8v bfr[6];
#pragma unroll
    for (int i = 0; i < 6; ++i) {
      int cb = (wv + 4 * i) * 16;        // interleaved col-tile ownership
      bfr[i] = *(const short8v*)&Bs[(p * NCOMB + cb + q) * 8];
    }
#pragma unroll
    for (int i = 0; i < 6; ++i)
#pragma unroll
      for (int rt = 0; rt < 4; ++rt)
        acc[i][rt] = __builtin_amdgcn_mfma_f32_16x16x32_bf16(af[rt], bfr[i],
                                                             acc[i][rt], 0, 0, 0);
    __syncthreads();
  }

  // ---- epilogue: G = pf@wo (raw, unscaled) for tiles i=4,5 (cols 256..383)
#pragma unroll
  for (int i = 4; i < 6; ++i) {
    int col = (wv + 4 * (i - 4)) * 16 + q;  // 0..127
#pragma unroll
    for (int rt = 0; rt < 4; ++rt)
#pragma unroll
      for (int r = 0; r < 4; ++r) {
        int row = rt * 16 + p * 4 + r;
        G[(size_t)(m0 + row) * O_DIM + col] = acc[i][rt][r];
      }
  }
  // ---- logit = sum_j relu(h_j + b1_j) * w2_j over the w1-part (i<4), f32
  float w2v[4], b1v[4];
#pragma unroll
  for (int i = 0; i < 4; ++i) {
    int col = (wv + 4 * i) * 16 + q;  // 0..255
    w2v[i] = w2[col];
    b1v[i] = b1[col];
  }
#pragma unroll
  for (int rt = 0; rt < 4; ++rt) {
    float pr[4] = {0.f, 0.f, 0.f, 0.f};
#pragma unroll
    for (int i = 0; i < 4; ++i)
#pragma unroll
      for (int r = 0; r < 4; ++r)
        pr[r] += fmaxf(acc[i][rt][r] + b1v[i], 0.f) * w2v[i];
#pragma unroll
    for (int mk = 1; mk < 16; mk <<= 1)
#pragma unroll
      for (int r = 0; r < 4; ++r) pr[r] += __shfl_xor(pr[r], mk);
    if (q == 0)
#pragma unroll
      for (int r = 0; r < 4; ++r) lpart[wv][rt * 16 + p * 4 + r] = pr[r];
  }
  __syncthreads();
  if (tid < 64) {
    float logit = lpart[0][tid] + lpart[1][tid] + lpart[2][tid] + lpart[3][tid] + b2[0];
    float sc = 1.f / (1.f + expf(-logit));
    int m = m0 + tid;
    scores[m] = sc;
    // borderline: bf16 logit error sigma ~5e-4 << 0.015/0.24 margin in logit space
    if (fabsf(sc - 0.4f) < 0.015f) {
      int idx = atomicAdd(bcount, 1);
      if (idx < 4096) blist[idx] = m;
    }
  }
}

// K2: exact fp32 recompute of borderline scores (one block per point)
__global__ __launch_bounds__(256) void fixup(
    const float* __restrict__ pf, const float* __restrict__ w1,
    const float* __restrict__ b1, const float* __restrict__ w2,
    const float* __restrict__ b2, const int* __restrict__ blist,
    const int* __restrict__ bcount, float* __restrict__ scores) {
  __shared__ float wpart[4];
  int cnt = *bcount;
  if (cnt > 4096) cnt = 4096;
  const int j = threadIdx.x;
  const int lane = j & 63, wv = j >> 6;
  for (int i = blockIdx.x; i < cnt; i += gridDim.x) {
    int m = blist[i];
    const float* prow = pf + (size_t)m * C_DIM;
    float acc = 0.f;
    for (int c = 0; c < C_DIM; ++c) acc = fmaf(prow[c], w1[c * H_DIM + j], acc);
    float v = fmaxf(acc + b1[j], 0.f) * w2[j];
#pragma unroll
    for (int mk = 1; mk < 64; mk <<= 1) v += __shfl_xor(v, mk);
    if (lane == 0) wpart[wv] = v;
    __syncthreads();
    if (j == 0) {
      float logit = wpart[0] + wpart[1] + wpart[2] + wpart[3] + b2[0];
      scores[m] = 1.f / (1.f + expf(-logit));
    }
    __syncthreads();
  }
}

// K3: per-batch stream-compaction scan (ballot + popcount)
__global__ __launch_bounds__(1024) void scan_sel(const float* __restrict__ scores,
                                                 int* __restrict__ pos_g,
                                                 int* __restrict__ counts) {
  __shared__ int wsum[16];
  __shared__ int srun;
  const int b = blockIdx.x;
  const int tid = threadIdx.x;
  const int lane = tid & 63, wv = tid >> 6;
  if (tid == 0) srun = 0;
  __syncthreads();
  for (int it = 0; it < 16; ++it) {
    int m = b * N_PTS + it * 1024 + tid;
    bool sel = scores[m] > 0.4f;
    unsigned long long bal = __ballot(sel);
    int wexc = __popcll(bal & ((1ull << lane) - 1ull));
    if (lane == 0) wsum[wv] = __popcll(bal);
    __syncthreads();
    int base = srun;
    for (int w = 0; w < wv; ++w) base += wsum[w];
    pos_g[m] = sel ? (b * N_PTS + base + wexc) : -1;
    __syncthreads();
    if (tid == 0) {
      int tot = 0;
#pragma unroll
      for (int w = 0; w < 16; ++w) tot += wsum[w];
      srun += tot;
    }
    __syncthreads();
  }
  if (tid == 0) counts[b] = srun;
}

// K4a: zero-fill only the padding tail rows (selection keeps ~99.98% of rows)
__global__ __launch_bounds__(256) void fill_tail(const int* __restrict__ counts,
                                                 float* __restrict__ out) {
  int m = blockIdx.x * 4 + (threadIdx.x >> 6);
  int lane = threadIdx.x & 63;
  int b = m >> 14, j = m & (N_PTS - 1);
  if (j < counts[b]) return;
  *(float2*)(out + (size_t)m * O_DIM + lane * 2) = make_float2(0.f, 0.f);
  if (lane == 0) {
    float* oc = out + OUT_COORD_OFF;
    oc[m * 3] = 0.f; oc[m * 3 + 1] = 0.f; oc[m * 3 + 2] = 0.f;
    out[OUT_MASK_OFF + m] = 1.f;  // padding row -> mask true
  }
}

// K4b: scatter selected rows: feats = score*G + bo, coords passthrough, mask
__global__ __launch_bounds__(256) void scatter(
    const float* __restrict__ G, const float* __restrict__ scores,
    const int* __restrict__ pos_g, const float* __restrict__ pc,
    const float* __restrict__ bo, float* __restrict__ out) {
  int m = blockIdx.x * 4 + (threadIdx.x >> 6);
  int lane = threadIdx.x & 63;
  int dst = pos_g[m];
  if (dst < 0) return;
  float sc = scores[m];
  float2 g = *(const float2*)(G + (size_t)m * O_DIM + lane * 2);
  float2 bv = *(const float2*)(bo + lane * 2);
  float2 o = make_float2(fmaf(g.x, sc, bv.x), fmaf(g.y, sc, bv.y));
  *(float2*)(out + (size_t)dst * O_DIM + lane * 2) = o;
  if (lane == 0) {
    float c0 = pc[m * 3], c1 = pc[m * 3 + 1], c2 = pc[m * 3 + 2];
    float* oc = out + OUT_COORD_OFF;
    oc[dst * 3] = c0; oc[dst * 3 + 1] = c1; oc[dst * 3 + 2] = c2;
    out[OUT_MASK_OFF + dst] = (c0 == 0.f || c1 == 0.f || c2 == 0.f) ? 1.f : 0.f;
  }
}

extern "C" void kernel_launch(void* const* d_in, const int* in_sizes, int n_in,
                              void* d_out, int out_size, void* d_ws, size_t ws_size,
                              hipStream_t stream) {
  const float* pf = (const float*)d_in[0];
  const float* pc = (const float*)d_in[1];
  const float* w1 = (const float*)d_in[2];
  const float* b1 = (const float*)d_in[3];
  const float* w2 = (const float*)d_in[4];
  const float* b2 = (const float*)d_in[5];
  const float* wo = (const float*)d_in[6];
  const float* bo = (const float*)d_in[7];
  float* out = (float*)d_out;
  char* ws = (char*)d_ws;

  unsigned short* Wt = (unsigned short*)(ws + WT_OFF);
  float* scores = (float*)(ws + SCORES_OFF);
  int* pos_g = (int*)(ws + POS_OFF);
  int* counts = (int*)(ws + COUNTS_OFF);
  int* bcount = (int*)(ws + BCNT_OFF);
  int* blist = (int*)(ws + BLIST_OFF);
  float* G = (float*)(ws + G_OFF);

  convert_w<<<960, 256, 0, stream>>>(w1, wo, Wt, bcount);
  gemm_fused<<<M_TOTAL / TM, 256, 0, stream>>>(pf, Wt, b1, w2, b2, scores, G,
                                               blist, bcount);
  fixup<<<120, 256, 0, stream>>>(pf, w1, b1, w2, b2, blist, bcount, scores);
  scan_sel<<<8, 1024, 0, stream>>>(scores, pos_g, counts);
  fill_tail<<<M_TOTAL / 4, 256, 0, stream>>>(counts, out);
  scatter<<<M_TOTAL / 4, 256, 0, stream>>>(G, scores, pos_g, pc, bo, out);
}

// Round 3
// 252.062 us; speedup vs baseline: 1.0965x; 1.0965x over previous
//
#include <hip/hip_runtime.h>
#include <hip/hip_bf16.h>

// ---------------------------------------------------------------------------
// KeypointWeighting fused: one GEMM kernel computes scores (w1/w2 MLP) and
// projection G=pf@wo, does in-block fp32 fixup of borderline scores, a
// decoupled-lookback stream-compaction scan (ticket-ordered), and scatters
// compacted feats/coords/mask directly. No G materialization.
// dims: B=8 N=16384 C=640 H=256 O=128, tiles of TM=64 rows, 256/batch.
// ---------------------------------------------------------------------------

typedef __attribute__((ext_vector_type(8))) short short8v;
typedef __attribute__((ext_vector_type(4))) float f32x4;

#define M_TOTAL 131072
#define C_DIM 640
#define H_DIM 256
#define O_DIM 128
#define NCOMB 384      // combined cols: 256 (w1) + 128 (wo)
#define TM 64
#define KSTEPS 20      // 640/32
#define N_PTS 16384
#define TILES_PER_B 256
#define NTILES 2048
#define THRL -0.4054651081f   // log(0.4/0.6); sigmoid(x)>0.4 <=> x>THRL
#define FIX_MARGIN 0.03f      // logit-space margin for fp32 recheck

#define OUT_COORD_OFF 16777216  // B*N*O floats
#define OUT_MASK_OFF  17170432  // + B*N*3

// ws layout (bytes)
#define WT_OFF     0u          // bf16 staged-order weights: 245760 elems
#define TSTATE_OFF 491520u     // u64 [2048] lookback states
#define TICKET_OFF 507904u     // i32 ticket
#define COUNTS_OFF 507908u     // i32 [8]

// direct global->LDS 16B copy
__device__ __forceinline__ void glds16(const void* g, void* l) {
  const __attribute__((address_space(1))) unsigned int* gp =
      reinterpret_cast<const __attribute__((address_space(1))) unsigned int*>(
          reinterpret_cast<uintptr_t>(g));
  __attribute__((address_space(3))) unsigned int* lp =
      reinterpret_cast<__attribute__((address_space(3))) unsigned int*>(
          reinterpret_cast<uintptr_t>(l));
  __builtin_amdgcn_global_load_lds(gp, lp, 16, 0, 0);
}

__device__ __forceinline__ unsigned int f2bf_bits(float f) {
  unsigned int u = __builtin_bit_cast(unsigned int, f);
  return (u + 0x7fffu + ((u >> 16) & 1u)) >> 16;  // RNE, bits in low 16
}
__device__ __forceinline__ unsigned int pack_bf2(float lo, float hi) {
  return f2bf_bits(lo) | (f2bf_bits(hi) << 16);
}

// K0: pack [w1 | wo] into bf16 in the EXACT staging order the GEMM consumes:
// elem o = ((ks*1536 + n*4 + kg)*8 + e)  holds  W[k = ks*32+kg*8+e][n]
// (n<256 -> w1 col n, else wo col n-256). Also zero lookback state + ticket.
__global__ __launch_bounds__(256) void convert_w(const float* __restrict__ w1,
                                                 const float* __restrict__ wo,
                                                 unsigned short* __restrict__ Wt2,
                                                 unsigned long long* __restrict__ tstate,
                                                 int* __restrict__ ticket) {
  int o = blockIdx.x * 256 + threadIdx.x;  // 960 blocks
  if (o < NTILES) tstate[o] = 0ull;
  if (o == NTILES) *ticket = 0;
  if (o < NCOMB * C_DIM) {
    int e = o & 7;
    int chunk = o >> 3;
    int ks = chunk / 1536;
    int r = chunk - ks * 1536;
    int n = r >> 2, kg = r & 3;
    int k = ks * 32 + kg * 8 + e;
    float v = (n < H_DIM) ? w1[k * H_DIM + n] : wo[k * O_DIM + (n - H_DIM)];
    Wt2[o] = (unsigned short)f2bf_bits(v);
  }
}

// K1: fused GEMM + score + fixup + lookback scan + scatter
__global__ __launch_bounds__(256) void gemm_fused(
    const float* __restrict__ pf, const unsigned short* __restrict__ Wt2,
    const float* __restrict__ w1, const float* __restrict__ b1,
    const float* __restrict__ w2, const float* __restrict__ b2,
    const float* __restrict__ pc, const float* __restrict__ bo,
    unsigned long long* __restrict__ tstate, int* __restrict__ ticket,
    int* __restrict__ counts, float* __restrict__ out) {
  __shared__ __align__(16) unsigned short As[4 * 64 * 8];     // 4 KB
  __shared__ __align__(16) unsigned short Bs[1536 * 8];       // 24 KB
  __shared__ float lpart[4][64];
  __shared__ float llog[64];
  __shared__ int dstrow[64];
  __shared__ float srow[64];
  __shared__ int s_tile;
  __shared__ unsigned long long s_fixmask;

  const int tid = threadIdx.x;
  const int lane = tid & 63;
  const int wv = tid >> 6;
  const int q = lane & 15;
  const int p = lane >> 4;

  // ticket-ordered tile assignment: guarantees lookback predecessors are
  // resident regardless of HW dispatch order (rocPRIM pattern)
  if (tid == 0) s_tile = atomicAdd(ticket, 1);
  __syncthreads();
  const int tile = s_tile;
  const int m0 = tile * TM;

  f32x4 acc[6][4];
#pragma unroll
  for (int i = 0; i < 6; ++i)
#pragma unroll
    for (int rt = 0; rt < 4; ++rt) acc[i][rt] = (f32x4){0.f, 0.f, 0.f, 0.f};

  const int ar = tid >> 2;       // A staging row
  const int akg = tid & 3;       // A staging k-group
  const float* asrc = pf + (size_t)(m0 + ar) * C_DIM + akg * 8;
  const unsigned short* bsrc = Wt2 + (size_t)tid * 8;

  for (int ks = 0; ks < KSTEPS; ++ks) {
    {  // stage A: 64x32 f32 -> bf16 (manual RNE pack)
      float4 f0 = *(const float4*)(asrc + ks * 32);
      float4 f1 = *(const float4*)(asrc + ks * 32 + 4);
      uint4 pk;
      pk.x = pack_bf2(f0.x, f0.y);
      pk.y = pack_bf2(f0.z, f0.w);
      pk.z = pack_bf2(f1.x, f1.y);
      pk.w = pack_bf2(f1.z, f1.w);
      *(uint4*)&As[(akg * 64 + ar) * 8] = pk;
    }
    // stage B: 24 KB via global_load_lds_dwordx4, fully contiguous streams
#pragma unroll
    for (int u = 0; u < 6; ++u)
      glds16(bsrc + (size_t)(ks * 1536 + u * 256) * 8, &Bs[(u * 256 + wv * 64) * 8]);
    __syncthreads();

    short8v af[4];
#pragma unroll
    for (int rt = 0; rt < 4; ++rt)
      af[rt] = *(const short8v*)&As[(p * 64 + rt * 16 + q) * 8];
#pragma unroll
    for (int i = 0; i < 6; ++i) {
      const int cb = (wv + 4 * i) * 16;
      short8v bfv = *(const short8v*)&Bs[((cb + q) * 4 + p) * 8];
#pragma unroll
      for (int rt = 0; rt < 4; ++rt)
        acc[i][rt] = __builtin_amdgcn_mfma_f32_16x16x32_bf16(af[rt], bfv, acc[i][rt], 0, 0, 0);
    }
    __syncthreads();
  }

  // ---- logits: sum_j relu(h_j+b1_j)*w2_j over col-tiles i<4 (cols 0..255)
  float w2v[4], b1v[4];
#pragma unroll
  for (int i = 0; i < 4; ++i) {
    int col = (wv + 4 * i) * 16 + q;
    w2v[i] = w2[col];
    b1v[i] = b1[col];
  }
#pragma unroll
  for (int rt = 0; rt < 4; ++rt) {
    float pr[4] = {0.f, 0.f, 0.f, 0.f};
#pragma unroll
    for (int i = 0; i < 4; ++i)
#pragma unroll
      for (int r = 0; r < 4; ++r)
        pr[r] += fmaxf(acc[i][rt][r] + b1v[i], 0.f) * w2v[i];
#pragma unroll
    for (int mk = 1; mk < 16; mk <<= 1)
#pragma unroll
      for (int r = 0; r < 4; ++r) pr[r] += __shfl_xor(pr[r], mk);
    if (q == 0)
#pragma unroll
      for (int r = 0; r < 4; ++r) lpart[wv][rt * 16 + p * 4 + r] = pr[r];
  }
  __syncthreads();

  float logit0 = 0.f;
  bool nf = false;
  if (wv == 0) {
    logit0 = lpart[0][tid] + lpart[1][tid] + lpart[2][tid] + lpart[3][tid] + b2[0];
    llog[tid] = logit0;
    nf = fabsf(logit0 - THRL) < FIX_MARGIN;
  }
  unsigned long long fm = __ballot(nf);
  if (tid == 0) s_fixmask = fm;
  __syncthreads();

  // ---- exact fp32 recompute of borderline rows (expected ~0.4/block)
  unsigned long long fixmask = s_fixmask;
  while (fixmask) {
    int row = __ffsll(fixmask) - 1;
    fixmask &= fixmask - 1;
    const float* prow = pf + (size_t)(m0 + row) * C_DIM;
    float a0 = 0.f, a1 = 0.f;
    for (int c = 0; c < C_DIM; c += 2) {
      a0 = fmaf(prow[c], w1[(size_t)c * H_DIM + tid], a0);
      a1 = fmaf(prow[c + 1], w1[(size_t)(c + 1) * H_DIM + tid], a1);
    }
    float v = fmaxf(a0 + a1 + b1[tid], 0.f) * w2[tid];
#pragma unroll
    for (int mk = 1; mk < 64; mk <<= 1) v += __shfl_xor(v, mk);
    if (lane == 0) lpart[0][wv] = v;
    __syncthreads();
    if (tid == 0)
      llog[row] = lpart[0][0] + lpart[0][1] + lpart[0][2] + lpart[0][3] + b2[0];
    __syncthreads();
  }

  // ---- selection + decoupled-lookback prefix scan (wave 0 = rows)
  float flog = 0.f;
  bool sel = false;
  if (wv == 0) {
    flog = llog[tid];
    sel = flog > THRL;
  }
  unsigned long long selmask = __ballot(sel);
  if (wv == 0) {
    const int tb = tile & (TILES_PER_B - 1);
    const int cbase = tile - tb;
    int agg = __popcll(selmask);
    if (tid == 0) {
      unsigned long long fl = (tb == 0) ? 2ull : 1ull;
      __hip_atomic_store(&tstate[tile], (fl << 32) | (unsigned int)agg,
                         __ATOMIC_RELAXED, __HIP_MEMORY_SCOPE_AGENT);
    }
    int excl = 0;
    if (tb > 0) {
      int offset = tb - 1;
      while (true) {
        int idx = offset - tid;
        unsigned long long s = 0;
        if (idx >= 0) {
          do {
            s = __hip_atomic_load(&tstate[cbase + idx], __ATOMIC_RELAXED,
                                  __HIP_MEMORY_SCOPE_AGENT);
          } while (!(s >> 32));
        }
        unsigned flag = (unsigned)(s >> 32);
        unsigned long long pm = __ballot(flag == 2u);
        int val = (int)(s & 0xffffffffull);
        int contrib;
        if (pm) {
          int k = __ffsll(pm) - 1;  // nearest tile with inclusive prefix
          contrib = (tid <= k) ? val : 0;
        } else {
          contrib = (idx >= 0) ? val : 0;
        }
#pragma unroll
        for (int mk = 1; mk < 64; mk <<= 1) contrib += __shfl_xor(contrib, mk);
        excl += contrib;
        if (pm) break;
        offset -= 64;
      }
      if (tid == 0)
        __hip_atomic_store(&tstate[tile], (2ull << 32) | (unsigned int)(excl + agg),
                           __ATOMIC_RELAXED, __HIP_MEMORY_SCOPE_AGENT);
    }
    int below = __popcll(selmask & ((1ull << tid) - 1ull));
    int bb = (tile >> 8) * N_PTS;
    dstrow[tid] = sel ? (bb + excl + below) : -1;
    srow[tid] = 1.f / (1.f + expf(-flog));
    if (tid == 0 && tb == TILES_PER_B - 1) counts[tile >> 8] = excl + agg;
  }
  __syncthreads();

  // ---- coords + mask scatter (row owners)
  if (wv == 0 && dstrow[tid] >= 0) {
    int dst = dstrow[tid];
    int m = m0 + tid;
    float c0 = pc[m * 3], c1 = pc[m * 3 + 1], c2 = pc[m * 3 + 2];
    float* oc = out + OUT_COORD_OFF;
    oc[dst * 3] = c0; oc[dst * 3 + 1] = c1; oc[dst * 3 + 2] = c2;
    out[OUT_MASK_OFF + dst] = (c0 == 0.f || c1 == 0.f || c2 == 0.f) ? 1.f : 0.f;
  }

  // ---- feats scatter: out[dst] = score * (pf@wo) + bo  (col-tiles i=4,5)
  const float bo0 = bo[wv * 16 + q];
  const float bo1 = bo[(wv + 4) * 16 + q];
#pragma unroll
  for (int i = 4; i < 6; ++i) {
    const int col = (wv + 4 * (i - 4)) * 16 + q;
    const float bov = (i == 4) ? bo0 : bo1;
#pragma unroll
    for (int rt = 0; rt < 4; ++rt)
#pragma unroll
      for (int r = 0; r < 4; ++r) {
        int row = rt * 16 + p * 4 + r;
        int dst = dstrow[row];
        if (dst >= 0)
          out[(size_t)dst * O_DIM + col] = fmaf(acc[i][rt][r], srow[row], bov);
      }
  }
}

// K2: zero-fill padding tail rows (j >= count[b]); mask=1 there
__global__ __launch_bounds__(256) void fill_tail(const int* __restrict__ counts,
                                                 float* __restrict__ out) {
  int m = blockIdx.x * 4 + (threadIdx.x >> 6);
  int lane = threadIdx.x & 63;
  int b = m >> 14, j = m & (N_PTS - 1);
  if (j < counts[b]) return;
  *(float2*)(out + (size_t)m * O_DIM + lane * 2) = make_float2(0.f, 0.f);
  if (lane == 0) {
    float* oc = out + OUT_COORD_OFF;
    oc[m * 3] = 0.f; oc[m * 3 + 1] = 0.f; oc[m * 3 + 2] = 0.f;
    out[OUT_MASK_OFF + m] = 1.f;
  }
}

extern "C" void kernel_launch(void* const* d_in, const int* in_sizes, int n_in,
                              void* d_out, int out_size, void* d_ws, size_t ws_size,
                              hipStream_t stream) {
  const float* pf = (const float*)d_in[0];
  const float* pc = (const float*)d_in[1];
  const float* w1 = (const float*)d_in[2];
  const float* b1 = (const float*)d_in[3];
  const float* w2 = (const float*)d_in[4];
  const float* b2 = (const float*)d_in[5];
  const float* wo = (const float*)d_in[6];
  const float* bo = (const float*)d_in[7];
  float* out = (float*)d_out;
  char* ws = (char*)d_ws;

  unsigned short* Wt2 = (unsigned short*)(ws + WT_OFF);
  unsigned long long* tstate = (unsigned long long*)(ws + TSTATE_OFF);
  int* ticket = (int*)(ws + TICKET_OFF);
  int* counts = (int*)(ws + COUNTS_OFF);

  convert_w<<<960, 256, 0, stream>>>(w1, wo, Wt2, tstate, ticket);
  gemm_fused<<<NTILES, 256, 0, stream>>>(pf, Wt2, w1, b1, w2, b2, pc, bo,
                                         tstate, ticket, counts, out);
  fill_tail<<<M_TOTAL / 4, 256, 0, stream>>>(counts, out);
}

// Round 4
// 219.417 us; speedup vs baseline: 1.2597x; 1.1488x over previous
//
#include <hip/hip_runtime.h>
#include <hip/hip_bf16.h>

// ---------------------------------------------------------------------------
// KeypointWeighting fused: one GEMM kernel computes scores (w1/w2 MLP) and
// projection pf@wo, in-block fp32 fixup of borderline scores, decoupled-
// lookback stream compaction, direct scatter of feats/coords/mask.
// R4: 8-wave blocks (48 acc VGPR/wave), XOR-swizzled LDS (conflict-free
// reads), 2-phase double-buffered pipeline with 1 barrier per K-step.
// dims: B=8 N=16384 C=640 H=256 O=128, tiles of TM=64 rows.
// ---------------------------------------------------------------------------

typedef __attribute__((ext_vector_type(8))) short short8v;
typedef __attribute__((ext_vector_type(4))) float f32x4;

#define M_TOTAL 131072
#define C_DIM 640
#define H_DIM 256
#define O_DIM 128
#define NCOMB 384      // combined cols: 256 (w1) + 128 (wo)
#define TM 64
#define KSTEPS 20      // 640/32
#define N_PTS 16384
#define TILES_PER_B 256
#define NTILES 2048
#define THRL -0.4054651081f   // log(0.4/0.6); sigmoid(x)>0.4 <=> x>THRL
#define FIX_MARGIN 0.03f      // logit-space margin for fp32 recheck

#define OUT_COORD_OFF 16777216  // B*N*O floats
#define OUT_MASK_OFF  17170432  // + B*N*3

// ws layout (bytes)
#define WT_OFF     0u          // bf16 staged-order weights: 245760 elems
#define TSTATE_OFF 491520u     // u64 [2048] lookback states
#define TICKET_OFF 507904u     // i32 ticket
#define COUNTS_OFF 507908u     // i32 [8]

// LDS swizzles (involutions).
// A tile: 256 granules of 16B; u = kg*64 + row. Read lanes share u&7 and
// differ in bit3 (q hi) / bits6-7 (kg) -> fold those into the low 3 bits.
__device__ __forceinline__ int swzA(int u) {
  return u ^ (((u >> 3) & 1) | (((u >> 6) & 3) << 1));
}
// B tile: 1536 granules of 16B; u = n*4 + kg. Read lanes share u&7, differ
// in bits3-5 (q>>1) -> XOR them in.
__device__ __forceinline__ int swzB(int u) { return u ^ ((u >> 3) & 7); }

// direct global->LDS 16B copy
__device__ __forceinline__ void glds16(const void* g, void* l) {
  const __attribute__((address_space(1))) unsigned int* gp =
      reinterpret_cast<const __attribute__((address_space(1))) unsigned int*>(
          reinterpret_cast<uintptr_t>(g));
  __attribute__((address_space(3))) unsigned int* lp =
      reinterpret_cast<__attribute__((address_space(3))) unsigned int*>(
          reinterpret_cast<uintptr_t>(l));
  __builtin_amdgcn_global_load_lds(gp, lp, 16, 0, 0);
}

__device__ __forceinline__ unsigned int f2bf_bits(float f) {
  unsigned int u = __builtin_bit_cast(unsigned int, f);
  return (u + 0x7fffu + ((u >> 16) & 1u)) >> 16;  // RNE, bits in low 16
}
__device__ __forceinline__ unsigned int pack_bf2(float lo, float hi) {
  return f2bf_bits(lo) | (f2bf_bits(hi) << 16);
}

// K0: pack [w1 | wo] bf16 into the PHYSICAL staging order the GEMM consumes.
// Physical slot r (16B, 0..1535 per kstep) holds logical fragment
// u = swzB(r) = n*4+kg (n = combined col, kg = k-group), elems k=ks*32+kg*8+e.
__global__ __launch_bounds__(256) void convert_w(const float* __restrict__ w1,
                                                 const float* __restrict__ wo,
                                                 unsigned short* __restrict__ Wt2,
                                                 unsigned long long* __restrict__ tstate,
                                                 int* __restrict__ ticket) {
  int o = blockIdx.x * 256 + threadIdx.x;  // 960 blocks x 256 = 245760
  if (o < NTILES) tstate[o] = 0ull;
  if (o == NTILES) *ticket = 0;
  if (o < NCOMB * C_DIM) {
    int e = o & 7;
    int chunk = o >> 3;
    int ks = chunk / 1536;
    int r = chunk - ks * 1536;
    int u = swzB(r);
    int n = u >> 2, kg = u & 3;
    int k = ks * 32 + kg * 8 + e;
    float v = (n < H_DIM) ? w1[k * H_DIM + n] : wo[k * O_DIM + (n - H_DIM)];
    Wt2[o] = (unsigned short)f2bf_bits(v);
  }
}

// K1: fused GEMM + score + fixup + lookback scan + scatter. 512 threads.
__global__ __launch_bounds__(512, 4) void gemm_fused(
    const float* __restrict__ pf, const unsigned short* __restrict__ Wt2,
    const float* __restrict__ w1, const float* __restrict__ b1,
    const float* __restrict__ w2, const float* __restrict__ b2,
    const float* __restrict__ pc, const float* __restrict__ bo,
    unsigned long long* __restrict__ tstate, int* __restrict__ ticket,
    int* __restrict__ counts, float* __restrict__ out) {
  __shared__ __align__(16) unsigned short As[2][256 * 8];    // 2 x 4 KB
  __shared__ __align__(16) unsigned short Bs[2][1536 * 8];   // 2 x 24 KB
  __shared__ float lpart[8][64];
  __shared__ float llog[64];
  __shared__ int dstrow[64];
  __shared__ float srow[64];
  __shared__ int s_tile;
  __shared__ unsigned long long s_fixmask;

  const int tid = threadIdx.x;
  const int lane = tid & 63;
  const int wv = tid >> 6;       // 0..7
  const int q = lane & 15;
  const int p = lane >> 4;

  if (tid == 0) s_tile = atomicAdd(ticket, 1);
  __syncthreads();
  const int tile = s_tile;
  const int m0 = tile * TM;

  f32x4 acc[3][4];
#pragma unroll
  for (int i = 0; i < 3; ++i)
#pragma unroll
    for (int rt = 0; rt < 4; ++rt) acc[i][rt] = (f32x4){0.f, 0.f, 0.f, 0.f};

  const int ar = tid >> 3;       // A staging row 0..63
  const int ah = tid & 7;        // A staging half-kgroup (4 floats)
  const float* asrc = pf + (size_t)(m0 + ar) * C_DIM + ah * 4;
  const int awp = swzA(((ah >> 1) << 6) + ar) * 8 + (ah & 1) * 4;  // ushort idx

  // ---- prologue: stage tile 0
  {
    float4 ra = *(const float4*)(asrc);
#pragma unroll
    for (int u = 0; u < 3; ++u)
      glds16(Wt2 + (size_t)(u * 512 + tid) * 8, &Bs[0][(u * 512 + tid) * 8]);
    *(uint2*)&As[0][awp] = make_uint2(pack_bf2(ra.x, ra.y), pack_bf2(ra.z, ra.w));
    __syncthreads();  // implicit vmcnt(0)+lgkmcnt(0) drain
  }

  // ---- main loop: 1 barrier per K-step, prefetch t+1 under compute on t
#pragma unroll 2
  for (int t = 0; t < KSTEPS; ++t) {
    const int cur = t & 1;
    float4 rn;
    if (t < KSTEPS - 1) {
      rn = *(const float4*)(asrc + (t + 1) * 32);
#pragma unroll
      for (int u = 0; u < 3; ++u)
        glds16(Wt2 + (size_t)((t + 1) * 1536 + u * 512 + tid) * 8,
               &Bs[cur ^ 1][(u * 512 + tid) * 8]);
    }
    short8v af[4];
#pragma unroll
    for (int rt = 0; rt < 4; ++rt)
      af[rt] = *(const short8v*)&As[cur][swzA((p << 6) + rt * 16 + q) * 8];
#pragma unroll
    for (int i = 0; i < 3; ++i) {
      const int ub = (((wv + 8 * i) * 16 + q) << 2) + p;
      short8v bfv = *(const short8v*)&Bs[cur][swzB(ub) * 8];
#pragma unroll
      for (int rt = 0; rt < 4; ++rt)
        acc[i][rt] = __builtin_amdgcn_mfma_f32_16x16x32_bf16(af[rt], bfv, acc[i][rt], 0, 0, 0);
    }
    if (t < KSTEPS - 1)
      *(uint2*)&As[cur ^ 1][awp] = make_uint2(pack_bf2(rn.x, rn.y), pack_bf2(rn.z, rn.w));
    __syncthreads();
  }

  // ---- logits: cols 0..255 live in col-tiles i=0,1 (col = (wv+8i)*16+q)
  float w2v[2], b1v[2];
#pragma unroll
  for (int i = 0; i < 2; ++i) {
    int col = (wv + 8 * i) * 16 + q;
    w2v[i] = w2[col];
    b1v[i] = b1[col];
  }
#pragma unroll
  for (int rt = 0; rt < 4; ++rt) {
    float pr[4] = {0.f, 0.f, 0.f, 0.f};
#pragma unroll
    for (int i = 0; i < 2; ++i)
#pragma unroll
      for (int r = 0; r < 4; ++r)
        pr[r] += fmaxf(acc[i][rt][r] + b1v[i], 0.f) * w2v[i];
#pragma unroll
    for (int mk = 1; mk < 16; mk <<= 1)
#pragma unroll
      for (int r = 0; r < 4; ++r) pr[r] += __shfl_xor(pr[r], mk);
    if (q == 0)
#pragma unroll
      for (int r = 0; r < 4; ++r) lpart[wv][rt * 16 + p * 4 + r] = pr[r];
  }
  __syncthreads();

  bool nf = false;
  if (wv == 0) {
    float lg = b2[0];
#pragma unroll
    for (int w = 0; w < 8; ++w) lg += lpart[w][tid];
    llog[tid] = lg;
    nf = fabsf(lg - THRL) < FIX_MARGIN;
  }
  unsigned long long fm = __ballot(nf);
  if (tid == 0) s_fixmask = fm;
  __syncthreads();

  // ---- exact fp32 recompute of borderline rows (threads 0..255 = H units)
  unsigned long long fixmask = s_fixmask;
  while (fixmask) {
    int row = __ffsll(fixmask) - 1;
    fixmask &= fixmask - 1;
    if (tid < 256) {
      const float* prow = pf + (size_t)(m0 + row) * C_DIM;
      float a0 = 0.f, a1 = 0.f;
      for (int c = 0; c < C_DIM; c += 2) {
        a0 = fmaf(prow[c], w1[(size_t)c * H_DIM + tid], a0);
        a1 = fmaf(prow[c + 1], w1[(size_t)(c + 1) * H_DIM + tid], a1);
      }
      float v = fmaxf(a0 + a1 + b1[tid], 0.f) * w2[tid];
#pragma unroll
      for (int mk = 1; mk < 64; mk <<= 1) v += __shfl_xor(v, mk);
      if (lane == 0) lpart[0][wv] = v;
    }
    __syncthreads();
    if (tid == 0)
      llog[row] = lpart[0][0] + lpart[0][1] + lpart[0][2] + lpart[0][3] + b2[0];
    __syncthreads();
  }

  // ---- selection + decoupled-lookback prefix scan (wave 0 = the 64 rows)
  float flog = 0.f;
  bool sel = false;
  if (wv == 0) {
    flog = llog[tid];
    sel = flog > THRL;
  }
  unsigned long long selmask = __ballot(sel);
  if (wv == 0) {
    const int tb = tile & (TILES_PER_B - 1);
    const int cbase = tile - tb;
    int agg = __popcll(selmask);
    if (tid == 0) {
      unsigned long long fl = (tb == 0) ? 2ull : 1ull;
      __hip_atomic_store(&tstate[tile], (fl << 32) | (unsigned int)agg,
                         __ATOMIC_RELAXED, __HIP_MEMORY_SCOPE_AGENT);
    }
    int excl = 0;
    if (tb > 0) {
      int offset = tb - 1;
      while (true) {
        int idx = offset - tid;
        unsigned long long s = 0;
        if (idx >= 0) {
          do {
            s = __hip_atomic_load(&tstate[cbase + idx], __ATOMIC_RELAXED,
                                  __HIP_MEMORY_SCOPE_AGENT);
          } while (!(s >> 32));
        }
        unsigned flag = (unsigned)(s >> 32);
        unsigned long long pm = __ballot(flag == 2u);
        int val = (int)(s & 0xffffffffull);
        int contrib;
        if (pm) {
          int k = __ffsll(pm) - 1;
          contrib = (tid <= k) ? val : 0;
        } else {
          contrib = (idx >= 0) ? val : 0;
        }
#pragma unroll
        for (int mk = 1; mk < 64; mk <<= 1) contrib += __shfl_xor(contrib, mk);
        excl += contrib;
        if (pm) break;
        offset -= 64;
      }
      if (tid == 0)
        __hip_atomic_store(&tstate[tile], (2ull << 32) | (unsigned int)(excl + agg),
                           __ATOMIC_RELAXED, __HIP_MEMORY_SCOPE_AGENT);
    }
    int below = __popcll(selmask & ((1ull << tid) - 1ull));
    int bb = (tile >> 8) * N_PTS;
    dstrow[tid] = sel ? (bb + excl + below) : -1;
    srow[tid] = 1.f / (1.f + expf(-flog));
    if (tid == 0 && tb == TILES_PER_B - 1) counts[tile >> 8] = excl + agg;
  }
  __syncthreads();

  // ---- coords + mask scatter (row owners)
  if (wv == 0 && dstrow[tid] >= 0) {
    int dst = dstrow[tid];
    int m = m0 + tid;
    float c0 = pc[m * 3], c1 = pc[m * 3 + 1], c2 = pc[m * 3 + 2];
    float* oc = out + OUT_COORD_OFF;
    oc[dst * 3] = c0; oc[dst * 3 + 1] = c1; oc[dst * 3 + 2] = c2;
    out[OUT_MASK_OFF + dst] = (c0 == 0.f || c1 == 0.f || c2 == 0.f) ? 1.f : 0.f;
  }

  // ---- feats scatter: out[dst] = score*(pf@wo) + bo (col-tile i=2)
  {
    const int gcol = wv * 16 + q;  // 0..127
    const float bov = bo[gcol];
#pragma unroll
    for (int rt = 0; rt < 4; ++rt)
#pragma unroll
      for (int r = 0; r < 4; ++r) {
        int row = rt * 16 + p * 4 + r;
        int dst = dstrow[row];
        if (dst >= 0)
          out[(size_t)dst * O_DIM + gcol] = fmaf(acc[2][rt][r], srow[row], bov);
      }
  }
}

// K2: zero-fill padding tail rows (j >= count[b]); mask=1 there
__global__ __launch_bounds__(256) void fill_tail(const int* __restrict__ counts,
                                                 float* __restrict__ out) {
  int m = blockIdx.x * 4 + (threadIdx.x >> 6);
  int lane = threadIdx.x & 63;
  int b = m >> 14, j = m & (N_PTS - 1);
  if (j < counts[b]) return;
  *(float2*)(out + (size_t)m * O_DIM + lane * 2) = make_float2(0.f, 0.f);
  if (lane == 0) {
    float* oc = out + OUT_COORD_OFF;
    oc[m * 3] = 0.f; oc[m * 3 + 1] = 0.f; oc[m * 3 + 2] = 0.f;
    out[OUT_MASK_OFF + m] = 1.f;
  }
}

extern "C" void kernel_launch(void* const* d_in, const int* in_sizes, int n_in,
                              void* d_out, int out_size, void* d_ws, size_t ws_size,
                              hipStream_t stream) {
  const float* pf = (const float*)d_in[0];
  const float* pc = (const float*)d_in[1];
  const float* w1 = (const float*)d_in[2];
  const float* b1 = (const float*)d_in[3];
  const float* w2 = (const float*)d_in[4];
  const float* b2 = (const float*)d_in[5];
  const float* wo = (const float*)d_in[6];
  const float* bo = (const float*)d_in[7];
  float* out = (float*)d_out;
  char* ws = (char*)d_ws;

  unsigned short* Wt2 = (unsigned short*)(ws + WT_OFF);
  unsigned long long* tstate = (unsigned long long*)(ws + TSTATE_OFF);
  int* ticket = (int*)(ws + TICKET_OFF);
  int* counts = (int*)(ws + COUNTS_OFF);

  convert_w<<<960, 256, 0, stream>>>(w1, wo, Wt2, tstate, ticket);
  gemm_fused<<<NTILES, 512, 0, stream>>>(pf, Wt2, w1, b1, w2, b2, pc, bo,
                                         tstate, ticket, counts, out);
  fill_tail<<<M_TOTAL / 4, 256, 0, stream>>>(counts, out);
}

// Round 5
// 200.368 us; speedup vs baseline: 1.3794x; 1.0951x over previous
//
#include <hip/hip_runtime.h>
#include <hip/hip_bf16.h>

// ---------------------------------------------------------------------------
// KeypointWeighting, de-fused pipeline (R5):
//   convert_w : pack [w1|wo] -> bf16 in staged (pre-swizzled) order
//   gemm      : per 64-row tile: MFMA GEMM -> logits (fp32 fixup) ->
//               selmask/aggregate + scaled feat rows (score*(pf@wo)+bo) to ws
//   scan      : per-batch exclusive scan of 256 tile aggregates (8 blocks)
//   scatter   : compact selected rows (feats from ws, coords, mask)
//   fill_tail : zero padding rows + mask=1
// dims: B=8 N=16384 C=640 H=256 O=128, M=131072, tiles 64 rows, 2048 tiles.
// ---------------------------------------------------------------------------

typedef __attribute__((ext_vector_type(8))) short short8v;
typedef __attribute__((ext_vector_type(4))) float f32x4;

#define M_TOTAL 131072
#define C_DIM 640
#define H_DIM 256
#define O_DIM 128
#define NCOMB 384
#define TM 64
#define KSTEPS 20
#define N_PTS 16384
#define TILES_PER_B 256
#define NTILES 2048
#define THRL -0.4054651081f   // log(0.4/0.6)
#define FIX_MARGIN 0.03f

#define OUT_COORD_OFF 16777216
#define OUT_MASK_OFF  17170432

// ws layout (bytes)
#define WT_OFF     0u          // bf16 staged weights, 245760 elems
#define TMASK_OFF  491520u     // u64 [2048] per-tile selection masks
#define TAGG_OFF   507904u     // i32 [2048] per-tile aggregates
#define TEXCL_OFF  516096u     // i32 [2048] per-tile exclusive bases
#define COUNTS_OFF 524288u     // i32 [8]
#define G_OFF      1572864u    // f32 [131072][128] scaled feats

// LDS swizzles (involutions), same as R4 (verified: 0 bank conflicts)
__device__ __forceinline__ int swzA(int u) {
  return u ^ (((u >> 3) & 1) | (((u >> 6) & 3) << 1));
}
__device__ __forceinline__ int swzB(int u) { return u ^ ((u >> 3) & 7); }

__device__ __forceinline__ void glds16(const void* g, void* l) {
  const __attribute__((address_space(1))) unsigned int* gp =
      reinterpret_cast<const __attribute__((address_space(1))) unsigned int*>(
          reinterpret_cast<uintptr_t>(g));
  __attribute__((address_space(3))) unsigned int* lp =
      reinterpret_cast<__attribute__((address_space(3))) unsigned int*>(
          reinterpret_cast<uintptr_t>(l));
  __builtin_amdgcn_global_load_lds(gp, lp, 16, 0, 0);
}

__device__ __forceinline__ unsigned int f2bf_bits(float f) {
  unsigned int u = __builtin_bit_cast(unsigned int, f);
  return (u + 0x7fffu + ((u >> 16) & 1u)) >> 16;
}
__device__ __forceinline__ unsigned int pack_bf2(float lo, float hi) {
  return f2bf_bits(lo) | (f2bf_bits(hi) << 16);
}

// K0: weights -> bf16 staged order (slot r holds logical granule swzB(r))
__global__ __launch_bounds__(256) void convert_w(const float* __restrict__ w1,
                                                 const float* __restrict__ wo,
                                                 unsigned short* __restrict__ Wt2) {
  int o = blockIdx.x * 256 + threadIdx.x;  // 960 x 256 = 245760
  if (o < NCOMB * C_DIM) {
    int e = o & 7;
    int chunk = o >> 3;
    int ks = chunk / 1536;
    int r = chunk - ks * 1536;
    int u = swzB(r);
    int n = u >> 2, kg = u & 3;
    int k = ks * 32 + kg * 8 + e;
    float v = (n < H_DIM) ? w1[k * H_DIM + n] : wo[k * O_DIM + (n - H_DIM)];
    Wt2[o] = (unsigned short)f2bf_bits(v);
  }
}

// K1: GEMM + scores (+fp32 fixup) + selmask/agg + scaled feat rows. 512 thr.
__global__ __launch_bounds__(512, 4) void gemm_fused(
    const float* __restrict__ pf, const unsigned short* __restrict__ Wt2,
    const float* __restrict__ w1, const float* __restrict__ b1,
    const float* __restrict__ w2, const float* __restrict__ b2,
    const float* __restrict__ bo, unsigned long long* __restrict__ tmask,
    int* __restrict__ tagg, float* __restrict__ G) {
  __shared__ __align__(16) unsigned short As[2][256 * 8];    // 2 x 4 KB
  __shared__ __align__(16) unsigned short Bs[2][1536 * 8];   // 2 x 24 KB
  __shared__ float lpart[8][64];
  __shared__ float llog[64];
  __shared__ float srow[64];
  __shared__ unsigned long long s_fixmask;

  const int tid = threadIdx.x;
  const int lane = tid & 63;
  const int wv = tid >> 6;
  const int q = lane & 15;
  const int p = lane >> 4;
  const int tile = blockIdx.x;
  const int m0 = tile * TM;

  f32x4 acc[3][4];
#pragma unroll
  for (int i = 0; i < 3; ++i)
#pragma unroll
    for (int rt = 0; rt < 4; ++rt) acc[i][rt] = (f32x4){0.f, 0.f, 0.f, 0.f};

  const int ar = tid >> 3;
  const int ah = tid & 7;
  const float* asrc = pf + (size_t)(m0 + ar) * C_DIM + ah * 4;
  const int awp = swzA(((ah >> 1) << 6) + ar) * 8 + (ah & 1) * 4;

  // prologue: stage tile 0, preload pf for tile 1 (depth-2 register pipe)
  float4 rB;
  {
    float4 rA = *(const float4*)(asrc);
    rB = *(const float4*)(asrc + 32);
#pragma unroll
    for (int u = 0; u < 3; ++u)
      glds16(Wt2 + (size_t)(u * 512 + tid) * 8, &Bs[0][(u * 512 + tid) * 8]);
    *(uint2*)&As[0][awp] = make_uint2(pack_bf2(rA.x, rA.y), pack_bf2(rA.z, rA.w));
    __syncthreads();
  }

#pragma unroll 2
  for (int t = 0; t < KSTEPS; ++t) {
    const int cur = t & 1;
    float4 rC;
    if (t + 2 < KSTEPS) rC = *(const float4*)(asrc + (t + 2) * 32);
    if (t + 1 < KSTEPS) {
#pragma unroll
      for (int u = 0; u < 3; ++u)
        glds16(Wt2 + (size_t)((t + 1) * 1536 + u * 512 + tid) * 8,
               &Bs[cur ^ 1][(u * 512 + tid) * 8]);
    }
    short8v af[4];
#pragma unroll
    for (int rt = 0; rt < 4; ++rt)
      af[rt] = *(const short8v*)&As[cur][swzA((p << 6) + rt * 16 + q) * 8];
#pragma unroll
    for (int i = 0; i < 3; ++i) {
      const int ub = (((wv + 8 * i) * 16 + q) << 2) + p;
      short8v bfv = *(const short8v*)&Bs[cur][swzB(ub) * 8];
#pragma unroll
      for (int rt = 0; rt < 4; ++rt)
        acc[i][rt] = __builtin_amdgcn_mfma_f32_16x16x32_bf16(af[rt], bfv, acc[i][rt], 0, 0, 0);
    }
    if (t + 1 < KSTEPS)
      *(uint2*)&As[cur ^ 1][awp] = make_uint2(pack_bf2(rB.x, rB.y), pack_bf2(rB.z, rB.w));
    rB = rC;
    __syncthreads();
  }

  // logits over col-tiles i=0,1 (cols 0..255)
  float w2v[2], b1v[2];
#pragma unroll
  for (int i = 0; i < 2; ++i) {
    int col = (wv + 8 * i) * 16 + q;
    w2v[i] = w2[col];
    b1v[i] = b1[col];
  }
#pragma unroll
  for (int rt = 0; rt < 4; ++rt) {
    float pr[4] = {0.f, 0.f, 0.f, 0.f};
#pragma unroll
    for (int i = 0; i < 2; ++i)
#pragma unroll
      for (int r = 0; r < 4; ++r)
        pr[r] += fmaxf(acc[i][rt][r] + b1v[i], 0.f) * w2v[i];
#pragma unroll
    for (int mk = 1; mk < 16; mk <<= 1)
#pragma unroll
      for (int r = 0; r < 4; ++r) pr[r] += __shfl_xor(pr[r], mk);
    if (q == 0)
#pragma unroll
      for (int r = 0; r < 4; ++r) lpart[wv][rt * 16 + p * 4 + r] = pr[r];
  }
  __syncthreads();

  bool nf = false;
  if (wv == 0) {
    float lg = b2[0];
#pragma unroll
    for (int w = 0; w < 8; ++w) lg += lpart[w][tid];
    llog[tid] = lg;
    nf = fabsf(lg - THRL) < FIX_MARGIN;
  }
  unsigned long long fm = __ballot(nf);
  if (tid == 0) s_fixmask = fm;
  __syncthreads();

  // exact fp32 recompute of borderline rows (rare)
  unsigned long long fixmask = s_fixmask;
  while (fixmask) {
    int row = __ffsll(fixmask) - 1;
    fixmask &= fixmask - 1;
    if (tid < 256) {
      const float* prow = pf + (size_t)(m0 + row) * C_DIM;
      float a0 = 0.f, a1 = 0.f;
      for (int c = 0; c < C_DIM; c += 2) {
        a0 = fmaf(prow[c], w1[(size_t)c * H_DIM + tid], a0);
        a1 = fmaf(prow[c + 1], w1[(size_t)(c + 1) * H_DIM + tid], a1);
      }
      float v = fmaxf(a0 + a1 + b1[tid], 0.f) * w2[tid];
#pragma unroll
      for (int mk = 1; mk < 64; mk <<= 1) v += __shfl_xor(v, mk);
      if (lane == 0) lpart[0][wv] = v;
    }
    __syncthreads();
    if (tid == 0)
      llog[row] = lpart[0][0] + lpart[0][1] + lpart[0][2] + lpart[0][3] + b2[0];
    __syncthreads();
  }

  // selection mask + aggregate + scores (no cross-block coupling)
  bool sel = false;
  float flog = 0.f;
  if (wv == 0) {
    flog = llog[tid];
    sel = flog > THRL;
  }
  unsigned long long selmask = __ballot(sel);
  if (wv == 0) {
    srow[tid] = 1.f / (1.f + expf(-flog));
    if (tid == 0) {
      tmask[tile] = selmask;
      tagg[tile] = __popcll(selmask);
    }
  }
  __syncthreads();

  // scaled feature rows to ws: G[m] = score*(pf@wo) + bo (col-tile i=2)
  {
    const int gcol = wv * 16 + q;
    const float bov = bo[gcol];
#pragma unroll
    for (int rt = 0; rt < 4; ++rt)
#pragma unroll
      for (int r = 0; r < 4; ++r) {
        int row = rt * 16 + p * 4 + r;
        G[(size_t)(m0 + row) * O_DIM + gcol] = fmaf(acc[2][rt][r], srow[row], bov);
      }
  }
}

// K2: per-batch exclusive scan of 256 tile aggregates. grid 8, block 256.
__global__ __launch_bounds__(256) void scan_tiles(const int* __restrict__ tagg,
                                                  int* __restrict__ texcl,
                                                  int* __restrict__ counts) {
  __shared__ int wsum[4];
  const int c = blockIdx.x, t = threadIdx.x;
  const int lane = t & 63, w = t >> 6;
  int v = tagg[c * 256 + t];
  int inc = v;
#pragma unroll
  for (int d = 1; d < 64; d <<= 1) {
    int n = __shfl_up(inc, d);
    if (lane >= d) inc += n;
  }
  if (lane == 63) wsum[w] = inc;
  __syncthreads();
  int base = 0;
#pragma unroll
  for (int ww = 0; ww < 4; ++ww)
    if (ww < w) base += wsum[ww];
  texcl[c * 256 + t] = base + inc - v;
  if (t == 255) counts[c] = base + inc;
}

// K3: compact selected rows. grid 2048, block 512 (wave wv: rows wv*8..+7)
__global__ __launch_bounds__(512) void scatter(
    const float* __restrict__ G, const unsigned long long* __restrict__ tmask,
    const int* __restrict__ texcl, const float* __restrict__ pc,
    float* __restrict__ out) {
  const int tile = blockIdx.x;
  const int tid = threadIdx.x;
  const int lane = tid & 63;
  const int wv = tid >> 6;
  const unsigned long long mask = tmask[tile];
  const int base = (tile >> 8) * N_PTS + texcl[tile];
  const int m0 = tile * TM;
#pragma unroll
  for (int j = 0; j < 8; ++j) {
    const int row = wv * 8 + j;
    if (!((mask >> row) & 1ull)) continue;
    const int dst = base + __popcll(mask & ((1ull << row) - 1ull));
    const int m = m0 + row;
    float2 g = *(const float2*)(G + (size_t)m * O_DIM + lane * 2);
    *(float2*)(out + (size_t)dst * O_DIM + lane * 2) = g;
    if (lane == 0) {
      float c0 = pc[m * 3], c1 = pc[m * 3 + 1], c2 = pc[m * 3 + 2];
      float* oc = out + OUT_COORD_OFF;
      oc[dst * 3] = c0; oc[dst * 3 + 1] = c1; oc[dst * 3 + 2] = c2;
      out[OUT_MASK_OFF + dst] = (c0 == 0.f || c1 == 0.f || c2 == 0.f) ? 1.f : 0.f;
    }
  }
}

// K4: zero-fill padding tail rows; mask=1 there
__global__ __launch_bounds__(256) void fill_tail(const int* __restrict__ counts,
                                                 float* __restrict__ out) {
  int m = blockIdx.x * 4 + (threadIdx.x >> 6);
  int lane = threadIdx.x & 63;
  int b = m >> 14, j = m & (N_PTS - 1);
  if (j < counts[b]) return;
  *(float2*)(out + (size_t)m * O_DIM + lane * 2) = make_float2(0.f, 0.f);
  if (lane == 0) {
    float* oc = out + OUT_COORD_OFF;
    oc[m * 3] = 0.f; oc[m * 3 + 1] = 0.f; oc[m * 3 + 2] = 0.f;
    out[OUT_MASK_OFF + m] = 1.f;
  }
}

extern "C" void kernel_launch(void* const* d_in, const int* in_sizes, int n_in,
                              void* d_out, int out_size, void* d_ws, size_t ws_size,
                              hipStream_t stream) {
  const float* pf = (const float*)d_in[0];
  const float* pc = (const float*)d_in[1];
  const float* w1 = (const float*)d_in[2];
  const float* b1 = (const float*)d_in[3];
  const float* w2 = (const float*)d_in[4];
  const float* b2 = (const float*)d_in[5];
  const float* wo = (const float*)d_in[6];
  const float* bo = (const float*)d_in[7];
  float* out = (float*)d_out;
  char* ws = (char*)d_ws;

  unsigned short* Wt2 = (unsigned short*)(ws + WT_OFF);
  unsigned long long* tmask = (unsigned long long*)(ws + TMASK_OFF);
  int* tagg = (int*)(ws + TAGG_OFF);
  int* texcl = (int*)(ws + TEXCL_OFF);
  int* counts = (int*)(ws + COUNTS_OFF);
  float* G = (float*)(ws + G_OFF);

  convert_w<<<960, 256, 0, stream>>>(w1, wo, Wt2);
  gemm_fused<<<NTILES, 512, 0, stream>>>(pf, Wt2, w1, b1, w2, b2, bo,
                                         tmask, tagg, G);
  scan_tiles<<<8, 256, 0, stream>>>(tagg, texcl, counts);
  scatter<<<NTILES, 512, 0, stream>>>(G, tmask, texcl, pc, out);
  fill_tail<<<M_TOTAL / 4, 256, 0, stream>>>(counts, out);
}

// Round 6
// 197.181 us; speedup vs baseline: 1.4017x; 1.0162x over previous
//
#include <hip/hip_runtime.h>
#include <hip/hip_bf16.h>

// ---------------------------------------------------------------------------
// KeypointWeighting R6: TM=128 tile (24 MFMA/wave/K-step, 4x R5) to amortize
// the per-K-step barrier drain. De-fused pipeline (R5 structure):
//   convert_w -> gemm (scores + fixup + selmask + scaled G) -> scan ->
//   scatter -> fill_tail
// dims: B=8 N=16384 C=640 H=256 O=128, M=131072, 1024 tiles of 128 rows.
// ---------------------------------------------------------------------------

typedef __attribute__((ext_vector_type(8))) short short8v;
typedef __attribute__((ext_vector_type(4))) float f32x4;

#define M_TOTAL 131072
#define C_DIM 640
#define H_DIM 256
#define O_DIM 128
#define NCOMB 384
#define TM 128
#define KSTEPS 20
#define N_PTS 16384
#define TILES_PER_B 128
#define NTILES 1024
#define THRL -0.4054651081f   // log(0.4/0.6)
#define FIX_MARGIN 0.03f

#define OUT_COORD_OFF 16777216
#define OUT_MASK_OFF  17170432

// ws layout (bytes)
#define WT_OFF     0u          // bf16 staged weights, 245760 elems
#define TMASK_OFF  491520u     // u64 [1024][2] per-tile selection masks
#define TAGG_OFF   507904u     // i32 [1024]
#define TEXCL_OFF  512000u     // i32 [1024]
#define COUNTS_OFF 516096u     // i32 [8]
#define G_OFF      1572864u    // f32 [131072][128] scaled feats

// LDS swizzles (involutions). B: identical to R5 (measured 0 conflicts).
// A (512 granules, u = kg*128 + row): fold kg (bits 8:7) and row-bit3 into
// the low 3 bank-select bits — same construction as R5's verified swzA.
__device__ __forceinline__ int swzA2(int u) {
  return u ^ (((u >> 3) & 1) | (((u >> 7) & 3) << 1));
}
__device__ __forceinline__ int swzB(int u) { return u ^ ((u >> 3) & 7); }

__device__ __forceinline__ void glds16(const void* g, void* l) {
  const __attribute__((address_space(1))) unsigned int* gp =
      reinterpret_cast<const __attribute__((address_space(1))) unsigned int*>(
          reinterpret_cast<uintptr_t>(g));
  __attribute__((address_space(3))) unsigned int* lp =
      reinterpret_cast<__attribute__((address_space(3))) unsigned int*>(
          reinterpret_cast<uintptr_t>(l));
  __builtin_amdgcn_global_load_lds(gp, lp, 16, 0, 0);
}

__device__ __forceinline__ unsigned int f2bf_bits(float f) {
  unsigned int u = __builtin_bit_cast(unsigned int, f);
  return (u + 0x7fffu + ((u >> 16) & 1u)) >> 16;
}
__device__ __forceinline__ unsigned int pack_bf2(float lo, float hi) {
  return f2bf_bits(lo) | (f2bf_bits(hi) << 16);
}

// K0: weights -> bf16 staged order (slot r holds logical granule swzB(r))
__global__ __launch_bounds__(256) void convert_w(const float* __restrict__ w1,
                                                 const float* __restrict__ wo,
                                                 unsigned short* __restrict__ Wt2) {
  int o = blockIdx.x * 256 + threadIdx.x;  // 960 x 256 = 245760
  if (o < NCOMB * C_DIM) {
    int e = o & 7;
    int chunk = o >> 3;
    int ks = chunk / 1536;
    int r = chunk - ks * 1536;
    int u = swzB(r);
    int n = u >> 2, kg = u & 3;
    int k = ks * 32 + kg * 8 + e;
    float v = (n < H_DIM) ? w1[k * H_DIM + n] : wo[k * O_DIM + (n - H_DIM)];
    Wt2[o] = (unsigned short)f2bf_bits(v);
  }
}

// K1: 128-row GEMM tile + scores (+fp32 fixup) + selmask + scaled G rows.
// 512 threads = 8 waves, wave grid 2 row-groups (wr) x 4 col-groups (wc):
// wave owns row-tiles rt=0..3 (rows wr*64+rt*16) x col-tiles ct=wc*6+i.
__global__ __launch_bounds__(512, 3) void gemm_fused(
    const float* __restrict__ pf, const unsigned short* __restrict__ Wt2,
    const float* __restrict__ w1, const float* __restrict__ b1,
    const float* __restrict__ w2, const float* __restrict__ b2,
    const float* __restrict__ bo, unsigned long long* __restrict__ tmask,
    int* __restrict__ tagg, float* __restrict__ G) {
  __shared__ __align__(16) unsigned short As[2][512 * 8];    // 2 x 8 KB
  __shared__ __align__(16) unsigned short Bs[2][1536 * 8];   // 2 x 24 KB
  __shared__ float lpart[3][128];
  __shared__ float llog[128];
  __shared__ float srow[128];
  __shared__ float fsum[4];
  __shared__ unsigned long long s_fm[2];
  __shared__ unsigned long long s_msk[2];

  const int tid = threadIdx.x;
  const int lane = tid & 63;
  const int wv = tid >> 6;
  const int q = lane & 15;
  const int p = lane >> 4;
  const int wr = wv & 1;
  const int wc = wv >> 1;
  const int tile = blockIdx.x;
  const int m0 = tile * TM;

  f32x4 acc[6][4];
#pragma unroll
  for (int i = 0; i < 6; ++i)
#pragma unroll
    for (int rt = 0; rt < 4; ++rt) acc[i][rt] = (f32x4){0.f, 0.f, 0.f, 0.f};

  const int arow = tid >> 2;     // staging row 0..127
  const int akg = tid & 3;       // staging k-group
  const float* asrc = pf + (size_t)(m0 + arow) * C_DIM + akg * 8;
  const int awp = swzA2(akg * 128 + arow) * 8;  // ushort index of 16B granule

  // prologue: stage tile 0, preload pf tile 1 into regs
  float4 rB0, rB1;
  {
    float4 a0 = *(const float4*)(asrc);
    float4 a1 = *(const float4*)(asrc + 4);
#pragma unroll
    for (int u = 0; u < 3; ++u)
      glds16(Wt2 + (size_t)(u * 512 + tid) * 8, &Bs[0][(u * 512 + tid) * 8]);
    *(uint4*)&As[0][awp] = make_uint4(pack_bf2(a0.x, a0.y), pack_bf2(a0.z, a0.w),
                                      pack_bf2(a1.x, a1.y), pack_bf2(a1.z, a1.w));
    rB0 = *(const float4*)(asrc + 32);
    rB1 = *(const float4*)(asrc + 36);
    __syncthreads();
  }

#pragma unroll 2
  for (int t = 0; t < KSTEPS; ++t) {
    const int cur = t & 1;
    float4 rC0 = rB0, rC1 = rB1;
    if (t + 2 < KSTEPS) {
      rC0 = *(const float4*)(asrc + (t + 2) * 32);
      rC1 = *(const float4*)(asrc + (t + 2) * 32 + 4);
    }
    if (t + 1 < KSTEPS) {
#pragma unroll
      for (int u = 0; u < 3; ++u)
        glds16(Wt2 + (size_t)((t + 1) * 1536 + u * 512 + tid) * 8,
               &Bs[cur ^ 1][(u * 512 + tid) * 8]);
    }
    short8v af[4];
#pragma unroll
    for (int rt = 0; rt < 4; ++rt)
      af[rt] = *(const short8v*)&As[cur][swzA2(p * 128 + wr * 64 + rt * 16 + q) * 8];
#pragma unroll
    for (int i = 0; i < 6; ++i) {
      const int ub = (((wc * 6 + i) * 16 + q) << 2) + p;
      short8v bfv = *(const short8v*)&Bs[cur][swzB(ub) * 8];
#pragma unroll
      for (int rt = 0; rt < 4; ++rt)
        acc[i][rt] = __builtin_amdgcn_mfma_f32_16x16x32_bf16(af[rt], bfv, acc[i][rt], 0, 0, 0);
    }
    if (t + 1 < KSTEPS)
      *(uint4*)&As[cur ^ 1][awp] = make_uint4(pack_bf2(rB0.x, rB0.y), pack_bf2(rB0.z, rB0.w),
                                              pack_bf2(rB1.x, rB1.y), pack_bf2(rB1.z, rB1.w));
    rB0 = rC0; rB1 = rC1;
    __syncthreads();
  }

  // ---- logit partials: w1 cols = col-tiles 0..15. wc=0,1: 6 tiles;
  // wc=2: 4 tiles; wc=3: none. Deterministic per-slice accumulation.
  if (wc < 3) {
    float b1v[6], w2v[6];
#pragma unroll
    for (int i = 0; i < 6; ++i) {
      int ct = wc * 6 + i;
      if (ct < 16) {
        int col = ct * 16 + q;
        b1v[i] = b1[col];
        w2v[i] = w2[col];
      } else {
        b1v[i] = 0.f;
        w2v[i] = 0.f;
      }
    }
#pragma unroll
    for (int rt = 0; rt < 4; ++rt) {
      float pr[4] = {0.f, 0.f, 0.f, 0.f};
#pragma unroll
      for (int i = 0; i < 6; ++i) {
        if (wc * 6 + i < 16) {
#pragma unroll
          for (int r = 0; r < 4; ++r)
            pr[r] += fmaxf(acc[i][rt][r] + b1v[i], 0.f) * w2v[i];
        }
      }
#pragma unroll
      for (int mk = 1; mk < 16; mk <<= 1)
#pragma unroll
        for (int r = 0; r < 4; ++r) pr[r] += __shfl_xor(pr[r], mk);
      if (q == 0)
#pragma unroll
        for (int r = 0; r < 4; ++r)
          lpart[wc][wr * 64 + rt * 16 + p * 4 + r] = pr[r];
    }
  }
  __syncthreads();

  // ---- logits + borderline masks (rows 0..127 on waves 0,1)
  if (tid < 128) {
    float lg = lpart[0][tid] + lpart[1][tid] + lpart[2][tid] + b2[0];
    llog[tid] = lg;
    bool nf = fabsf(lg - THRL) < FIX_MARGIN;
    unsigned long long fm = __ballot(nf);
    if (lane == 0) s_fm[wv] = fm;
  }
  __syncthreads();

  // ---- exact fp32 recompute of borderline rows
#pragma unroll 1
  for (int h = 0; h < 2; ++h) {
    unsigned long long fixmask = s_fm[h];
    while (fixmask) {
      int row = h * 64 + (__ffsll(fixmask) - 1);
      fixmask &= fixmask - 1;
      if (tid < 256) {
        const float* prow = pf + (size_t)(m0 + row) * C_DIM;
        float a0 = 0.f, a1 = 0.f;
        for (int c = 0; c < C_DIM; c += 2) {
          a0 = fmaf(prow[c], w1[(size_t)c * H_DIM + tid], a0);
          a1 = fmaf(prow[c + 1], w1[(size_t)(c + 1) * H_DIM + tid], a1);
        }
        float v = fmaxf(a0 + a1 + b1[tid], 0.f) * w2[tid];
#pragma unroll
        for (int mk = 1; mk < 64; mk <<= 1) v += __shfl_xor(v, mk);
        if (lane == 0) fsum[wv] = v;
      }
      __syncthreads();
      if (tid == 0)
        llog[row] = fsum[0] + fsum[1] + fsum[2] + fsum[3] + b2[0];
      __syncthreads();
    }
  }

  // ---- selection masks + scores
  if (tid < 128) {
    float flog = llog[tid];
    bool sel = flog > THRL;
    unsigned long long mk = __ballot(sel);
    srow[tid] = 1.f / (1.f + expf(-flog));
    if (lane == 0) s_msk[wv] = mk;
  }
  __syncthreads();
  if (tid == 0) {
    tmask[2 * tile] = s_msk[0];
    tmask[2 * tile + 1] = s_msk[1];
    tagg[tile] = __popcll(s_msk[0]) + __popcll(s_msk[1]);
  }

  // ---- scaled feature rows: G[m] = score*(pf@wo)+bo. wo = col-tiles 16..23.
#pragma unroll
  for (int i = 0; i < 6; ++i) {
    int ct = wc * 6 + i;
    if (ct >= 16) {
      int gcol = (ct - 16) * 16 + q;  // 0..127
      float bov = bo[gcol];
#pragma unroll
      for (int rt = 0; rt < 4; ++rt)
#pragma unroll
        for (int r = 0; r < 4; ++r) {
          int row = wr * 64 + rt * 16 + p * 4 + r;
          G[(size_t)(m0 + row) * O_DIM + gcol] = fmaf(acc[i][rt][r], srow[row], bov);
        }
    }
  }
}

// K2: per-batch exclusive scan of 128 tile aggregates. grid 8, block 128.
__global__ __launch_bounds__(128) void scan_tiles(const int* __restrict__ tagg,
                                                  int* __restrict__ texcl,
                                                  int* __restrict__ counts) {
  __shared__ int ws0;
  const int c = blockIdx.x, t = threadIdx.x;
  const int lane = t & 63, w = t >> 6;
  int v = tagg[c * 128 + t];
  int inc = v;
#pragma unroll
  for (int d = 1; d < 64; d <<= 1) {
    int n = __shfl_up(inc, d);
    if (lane >= d) inc += n;
  }
  if (lane == 63 && w == 0) ws0 = inc;
  __syncthreads();
  int base = (w == 1) ? ws0 : 0;
  texcl[c * 128 + t] = base + inc - v;
  if (t == 127) counts[c] = base + inc;
}

// K3: compact selected rows. grid 1024, block 512 (wave wv: rows wv*16..+15)
__global__ __launch_bounds__(512) void scatter(
    const float* __restrict__ G, const unsigned long long* __restrict__ tmask,
    const int* __restrict__ texcl, const float* __restrict__ pc,
    float* __restrict__ out) {
  const int tile = blockIdx.x;
  const int tid = threadIdx.x;
  const int lane = tid & 63;
  const int wv = tid >> 6;
  const unsigned long long mk0 = tmask[2 * tile];
  const unsigned long long mk1 = tmask[2 * tile + 1];
  const int c0 = __popcll(mk0);
  const int base = (tile >> 7) * N_PTS + texcl[tile];
  const int m0 = tile * TM;
#pragma unroll
  for (int jj = 0; jj < 16; ++jj) {
    const int row = wv * 16 + jj;
    const unsigned long long mk = (row < 64) ? mk0 : mk1;
    const int rb = row & 63;
    if (!((mk >> rb) & 1ull)) continue;
    const int dst = base + __popcll(mk & ((1ull << rb) - 1ull)) + ((row < 64) ? 0 : c0);
    const int m = m0 + row;
    float2 g = *(const float2*)(G + (size_t)m * O_DIM + lane * 2);
    *(float2*)(out + (size_t)dst * O_DIM + lane * 2) = g;
    if (lane == 0) {
      float cx = pc[m * 3], cy = pc[m * 3 + 1], cz = pc[m * 3 + 2];
      float* oc = out + OUT_COORD_OFF;
      oc[dst * 3] = cx; oc[dst * 3 + 1] = cy; oc[dst * 3 + 2] = cz;
      out[OUT_MASK_OFF + dst] = (cx == 0.f || cy == 0.f || cz == 0.f) ? 1.f : 0.f;
    }
  }
}

// K4: zero-fill padding tail rows; mask=1 there
__global__ __launch_bounds__(256) void fill_tail(const int* __restrict__ counts,
                                                 float* __restrict__ out) {
  int m = blockIdx.x * 4 + (threadIdx.x >> 6);
  int lane = threadIdx.x & 63;
  int b = m >> 14, j = m & (N_PTS - 1);
  if (j < counts[b]) return;
  *(float2*)(out + (size_t)m * O_DIM + lane * 2) = make_float2(0.f, 0.f);
  if (lane == 0) {
    float* oc = out + OUT_COORD_OFF;
    oc[m * 3] = 0.f; oc[m * 3 + 1] = 0.f; oc[m * 3 + 2] = 0.f;
    out[OUT_MASK_OFF + m] = 1.f;
  }
}

extern "C" void kernel_launch(void* const* d_in, const int* in_sizes, int n_in,
                              void* d_out, int out_size, void* d_ws, size_t ws_size,
                              hipStream_t stream) {
  const float* pf = (const float*)d_in[0];
  const float* pc = (const float*)d_in[1];
  const float* w1 = (const float*)d_in[2];
  const float* b1 = (const float*)d_in[3];
  const float* w2 = (const float*)d_in[4];
  const float* b2 = (const float*)d_in[5];
  const float* wo = (const float*)d_in[6];
  const float* bo = (const float*)d_in[7];
  float* out = (float*)d_out;
  char* ws = (char*)d_ws;

  unsigned short* Wt2 = (unsigned short*)(ws + WT_OFF);
  unsigned long long* tmask = (unsigned long long*)(ws + TMASK_OFF);
  int* tagg = (int*)(ws + TAGG_OFF);
  int* texcl = (int*)(ws + TEXCL_OFF);
  int* counts = (int*)(ws + COUNTS_OFF);
  float* G = (float*)(ws + G_OFF);

  convert_w<<<960, 256, 0, stream>>>(w1, wo, Wt2);
  gemm_fused<<<NTILES, 512, 0, stream>>>(pf, Wt2, w1, b1, w2, b2, bo,
                                         tmask, tagg, G);
  scan_tiles<<<8, 128, 0, stream>>>(tagg, texcl, counts);
  scatter<<<NTILES, 512, 0, stream>>>(G, tmask, texcl, pc, out);
  fill_tail<<<M_TOTAL / 4, 256, 0, stream>>>(counts, out);
}